// Round 6
// baseline (407.263 us; speedup 1.0000x reference)
//
#include <hip/hip_runtime.h>
#include <hip/hip_bf16.h>

#define NN 50000
#define EE 800000
#define SCAN_B 2048
#define NB ((NN + SCAN_B - 1) / SCAN_B)   // 25 scan blocks
#define LOG2E 1.44269504088896340736f

// NOTE: harness materializes integer inputs as int32 -> edge_index is const int*.
// NOTE (r7): per-channel fp32 scatter atomics (~100M) = ~80us wall. Avoided.
// NOTE (r9): CSR holds real edges only; self-loop handled inline in agg kernels.
// NOTE (r12): aggregate x then project: FETCH 253->139MB confirmed.
// NOTE (r13/r14): deep per-wave pipelines REGRESS: avg degree 16 -> prologue
//             waste + VGPR 84 -> occ 28%. Measured BW ~ occupancy (Little's law):
//             72%/3.65, 46%/2.5, 28%/2.1 TB/s. Lean waves win.
// NOTE (r15): full-wave-per-edge aggs: lane=(head,chan) -> acc 8 floats, zero
//             shuffles, coalesced epilogue write; slots +4 ahead, payload +2;
//             e1 exps precomputed in scatter (body = unpack + 4 pk-fma).

typedef short bf16x8 __attribute__((ext_vector_type(8)));
typedef float f32x4  __attribute__((ext_vector_type(4)));
typedef float f32x2  __attribute__((ext_vector_type(2)));

__device__ __forceinline__ float bf2f(unsigned short u) {
    return __uint_as_float(((unsigned)u) << 16);
}
__device__ __forceinline__ unsigned short f2bf(float f) {
    unsigned b = __float_as_uint(f);
    b += 0x7fffu + ((b >> 16) & 1u);           // RNE
    return (unsigned short)(b >> 16);
}
__device__ __forceinline__ float2 bfpair(unsigned u) {
    return make_float2(__uint_as_float(u << 16), __uint_as_float(u & 0xffff0000u));
}
__device__ __forceinline__ f32x2 bfpair2(unsigned u) {
    f32x2 r;
    r.x = __uint_as_float(u << 16);
    r.y = __uint_as_float(u & 0xffff0000u);
    return r;
}

// ---------------- fused prep: v-proj + Asd + Wt casts + hist/rank + x cast ----
// v and Asd are pre-scaled by log2e: alphas live in exp2 domain downstream.
__global__ void k_prep(const float* __restrict__ We1, const float* __restrict__ ae1,
                       const float* __restrict__ We2, const float* __restrict__ ae2,
                       float* __restrict__ v,
                       const float* __restrict__ as1, const float* __restrict__ ad1,
                       float* __restrict__ Asd,
                       const float* __restrict__ W1, unsigned short* __restrict__ W1t,
                       const float* __restrict__ W2, unsigned short* __restrict__ W2t,
                       const int* __restrict__ ei, int* __restrict__ idg,
                       int* __restrict__ rank,
                       const float* __restrict__ x, unsigned short* __restrict__ xb) {
    int bid = blockIdx.x, t = threadIdx.x;
    if (bid == 0) {
        if (t < 8) {            // layer1: c=t>>2, h=t&3 -> v[c*4+h]
            int c = t >> 2, h = t & 3;
            float s = 0.f;
            for (int d = 0; d < 64; d++) s += We1[c * 256 + h * 64 + d] * ae1[h * 64 + d];
            v[c * 4 + h] = s * LOG2E;
        } else if (t < 10) {    // layer2: c=t-8 -> v[8+c]
            int c = t - 8;
            float s = 0.f;
            for (int d = 0; d < 128; d++) s += We2[c * 128 + d] * ae2[d];
            v[8 + c] = s * LOG2E;
        }
        // Asd[k*8+j]: j<4 -> sum_c W1[k,j*64+c]*as1[j,c]; j>=4 -> same with ad1
        #pragma unroll 1
        for (int idx = t; idx < 1024; idx += 256) {
            int k = idx >> 3, j = idx & 7;
            const float* a = (j < 4) ? as1 : ad1;
            int h = j & 3;
            float s = 0.f;
            for (int c = 0; c < 64; c++) s += W1[k * 256 + h * 64 + c] * a[h * 64 + c];
            Asd[idx] = s * LOG2E;
        }
    } else if (bid <= 256) {
        int idx = (bid - 1) * 256 + t;
        if (idx < 32768) {                 // W1: 128x256 -> 256x128
            int k = idx >> 8, n = idx & 255;
            W1t[n * 128 + k] = f2bf(W1[idx]);
        } else {                           // W2: 256x128 -> 128x256
            int i = idx - 32768;
            int k = i >> 7, n = i & 127;
            W2t[n * 256 + k] = f2bf(W2[i]);
        }
    } else if (bid <= 256 + 3125) {
        int e = (bid - 257) * 256 + t;
        if (e < EE) rank[e] = atomicAdd(&idg[ei[EE + e]], 1);
    } else {
        int i = (bid - 3382) * 256 + t;
        if (i < NN * 128 / 4) {
            float4 vv = ((const float4*)x)[i];
            ushort4 o;
            o.x = f2bf(vv.x); o.y = f2bf(vv.y); o.z = f2bf(vv.z); o.w = f2bf(vv.w);
            ((ushort4*)xb)[i] = o;
        }
    }
}

// ---------------- CSR build: 3-pass exclusive scan of idg -> rowptr -----------
__global__ void k_scan1(const int* __restrict__ idg, int* __restrict__ rowptr,
                        int* __restrict__ bsum) {
    __shared__ int sh[512];
    int t = threadIdx.x;
    int base = blockIdx.x * SCAN_B + t * 4;
    int v[4]; int s = 0;
    #pragma unroll
    for (int j = 0; j < 4; j++) {
        int i = base + j;
        v[j] = (i < NN) ? idg[i] : 0;
        s += v[j];
    }
    sh[t] = s;
    __syncthreads();
    for (int off = 1; off < 512; off <<= 1) {
        int a = (t >= off) ? sh[t - off] : 0;
        __syncthreads();
        sh[t] += a;
        __syncthreads();
    }
    int run = sh[t] - s;
    #pragma unroll
    for (int j = 0; j < 4; j++) {
        int i = base + j;
        if (i < NN) rowptr[i] = run;
        run += v[j];
    }
    if (t == 511) bsum[blockIdx.x] = sh[511];
}

__global__ void k_scan2(const int* __restrict__ bsum, int* __restrict__ boff,
                        int* __restrict__ rowptr) {
    if (threadIdx.x == 0) {
        int acc = 0;
        for (int b = 0; b < NB; b++) { boff[b] = acc; acc += bsum[b]; }
        rowptr[NN] = acc;      // == EE
    }
}

__global__ void k_scan3(int* __restrict__ rowptr, const int* __restrict__ boff) {
    int t = threadIdx.x;
    int i = blockIdx.x * SCAN_B + t * 4;
    int off = boff[blockIdx.x];
    #pragma unroll
    for (int j = 0; j < 4; j++)
        if (i + j < NN) rowptr[i + j] += off;
}

// ---------------- layer1 attn scalars: asrc/adst = x . Asd (factored) ---------
__global__ __launch_bounds__(256) void k_attn1(const unsigned short* __restrict__ xb,
                       const float* __restrict__ Asd,
                       float* __restrict__ asrc, float* __restrict__ adst) {
    int node = blockIdx.x * 4 + (threadIdx.x >> 6);
    if (node >= NN) return;
    int lane = threadIdx.x & 63;
    unsigned xw = *(const unsigned*)(xb + (size_t)node * 128 + lane * 2);
    float2 xc = bfpair(xw);
    const float4* A4 = (const float4*)Asd;     // [k][8] -> float4 pairs
    float4 s0 = A4[lane * 4 + 0];              // k=2l  src
    float4 d0 = A4[lane * 4 + 1];              // k=2l  dst
    float4 s1 = A4[lane * 4 + 2];              // k=2l+1 src
    float4 d1 = A4[lane * 4 + 3];              // k=2l+1 dst
    float r[8];
    r[0] = xc.x * s0.x + xc.y * s1.x;
    r[1] = xc.x * s0.y + xc.y * s1.y;
    r[2] = xc.x * s0.z + xc.y * s1.z;
    r[3] = xc.x * s0.w + xc.y * s1.w;
    r[4] = xc.x * d0.x + xc.y * d1.x;
    r[5] = xc.x * d0.y + xc.y * d1.y;
    r[6] = xc.x * d0.z + xc.y * d1.z;
    r[7] = xc.x * d0.w + xc.y * d1.w;
    #pragma unroll
    for (int off = 1; off < 64; off <<= 1)
        #pragma unroll
        for (int j = 0; j < 8; j++) r[j] += __shfl_xor(r[j], off);
    if (lane == 0) {
        *(float4*)(asrc + node * 4) = make_float4(r[0], r[1], r[2], r[3]);
        *(float4*)(adst + node * 4) = make_float4(r[4], r[5], r[6], r[7]);
    }
}

// ---------------- scatter + per-edge layer1 exps ------------------------------
// p = rowptr[dst] + rank[e]; slot[p] = {src, bf16 attrs}; e1[p] = exp2 of the 4
// leaky'd head alphas (asrc1[s] + adst1[d] + attr.v, all exp2-domain already).
__global__ void k_scatter(const int* __restrict__ ei, const float* __restrict__ eattr,
                          const int* __restrict__ rowptr, const int* __restrict__ rank,
                          const float* __restrict__ asrc, const float* __restrict__ adst,
                          const float* __restrict__ v,
                          int2* __restrict__ slot, float4* __restrict__ e1) {
    int e = blockIdx.x * blockDim.x + threadIdx.x;
    if (e >= EE) return;
    int s = ei[e], d = ei[EE + e];
    int p = rowptr[d] + rank[e];
    float2 a = ((const float2*)eattr)[e];
    unsigned a0 = f2bf(a.x), a1 = f2bf(a.y);
    slot[p] = make_int2(s, (int)(a0 | (a1 << 16)));
    float4 s4 = *(const float4*)(asrc + s * 4);
    float4 d4 = *(const float4*)(adst + d * 4);
    float al0 = s4.x + d4.x + a.x * v[0] + a.y * v[4];
    float al1 = s4.y + d4.y + a.x * v[1] + a.y * v[5];
    float al2 = s4.z + d4.z + a.x * v[2] + a.y * v[6];
    float al3 = s4.w + d4.w + a.x * v[3] + a.y * v[7];
    al0 = (al0 > 0.f) ? al0 : 0.2f * al0;
    al1 = (al1 > 0.f) ? al1 : 0.2f * al1;
    al2 = (al2 > 0.f) ? al2 : 0.2f * al2;
    al3 = (al3 > 0.f) ? al3 : 0.2f * al3;
    float4 ev;
    ev.x = __builtin_amdgcn_exp2f(al0);
    ev.y = __builtin_amdgcn_exp2f(al1);
    ev.z = __builtin_amdgcn_exp2f(al2);
    ev.w = __builtin_amdgcn_exp2f(al3);
    e1[p] = ev;
}

// ---------------- layer1 aggregate of X: full-wave per edge -------------------
// one wave / node; ALL 64 lanes process the same edge. lane = (head hp=lane>>4,
// chan-group ql=lane&15). Quarters share x-row addresses (coalesced broadcast:
// wave still fetches exactly 256B/edge). acc = 8 floats/lane; den/s0/s1 complete
// per lane -> ZERO shuffles; epilogue is a fully coalesced 1KB row write.
// Slots prefetched +4 edges (2-slot ring), payload (attr,e1,xrow) +2.
__global__ __launch_bounds__(256) void k_agg1x(const int* __restrict__ rowptr,
                       const int2* __restrict__ slot, const float* __restrict__ e1v,
                       const float* __restrict__ asrc, const float* __restrict__ adst,
                       const float* __restrict__ v,
                       const unsigned short* __restrict__ xb,
                       unsigned short* __restrict__ Sx) {
    int node = blockIdx.x * 4 + (threadIdx.x >> 6);
    if (node >= NN) return;
    int lane = threadIdx.x & 63;
    int hp = lane >> 4;          // head
    int ql = lane & 15;          // chan-group: owns ch [ql*8, ql*8+8) of head hp
    int beg = rowptr[node], end = rowptr[node + 1];
    int cnt = end - beg;
    int safe = max(end - 1, 0);
    const unsigned short* xbq = xb + ql * 8;

    f32x2 acc[4] = {};
    float den = 0.f, s0 = 0.f, s1 = 0.f;

    // payload stages (edges p, p+1) + slot ring (edges p+2, p+3)
    int atA, atB; float eA, eB; uint4 xA, xB;
    int2 rA, rB;
    {
        int iA = min(beg, safe), iB = min(beg + 1, safe);
        int2 sA = slot[iA], sB = slot[iB];
        atA = sA.y; atB = sB.y;
        eA = e1v[iA * 4 + hp]; eB = e1v[iB * 4 + hp];
        xA = *(const uint4*)(xbq + (size_t)(unsigned)sA.x * 128);
        xB = *(const uint4*)(xbq + (size_t)(unsigned)sB.x * 128);
        rA = slot[min(beg + 2, safe)];
        rB = slot[min(beg + 3, safe)];
    }

#define A1_DO(AT, EV, XR) { \
    f32x2 a = bfpair2((unsigned)(AT)); \
    s0 += a.x; s1 += a.y; den += (EV); \
    f32x2 E = {(EV), (EV)}; \
    acc[0] += E * bfpair2((XR).x); acc[1] += E * bfpair2((XR).y); \
    acc[2] += E * bfpair2((XR).z); acc[3] += E * bfpair2((XR).w); }

    int mend = beg + (cnt & ~1);
    #pragma unroll 1
    for (int p = beg; p < mend; p += 2) {
        A1_DO(atA, eA, xA);                        // edge p
        {   // payload A <- edge p+2 (ring slot arrived last iter)
            int i = min(p + 2, safe);
            atA = rA.y;
            eA = e1v[i * 4 + hp];
            xA = *(const uint4*)(xbq + (size_t)(unsigned)rA.x * 128);
            rA = slot[min(p + 4, safe)];
        }
        A1_DO(atB, eB, xB);                        // edge p+1
        {   // payload B <- edge p+3
            int i = min(p + 3, safe);
            atB = rB.y;
            eB = e1v[i * 4 + hp];
            xB = *(const uint4*)(xbq + (size_t)(unsigned)rB.x * 128);
            rB = slot[min(p + 5, safe)];
        }
    }
    if (cnt & 1) { A1_DO(atA, eA, xA); }           // edge mend (= end-1)
#undef A1_DO

    // self-loop: mean attrs over real edges (0 if none)
    float dg = fmaxf((float)cnt, 1.0f);
    float als = asrc[node * 4 + hp] + adst[node * 4 + hp]
              + (s0 / dg) * v[hp] + (s1 / dg) * v[4 + hp];
    als = (als > 0.f) ? als : 0.2f * als;
    float exs = __builtin_amdgcn_exp2f(als);
    den += exs;

    uint4 r = *(const uint4*)(xbq + (size_t)node * 128);
    f32x2 E = {exs, exs};
    acc[0] += E * bfpair2(r.x); acc[1] += E * bfpair2(r.y);
    acc[2] += E * bfpair2(r.z); acc[3] += E * bfpair2(r.w);

    float inv = 1.f / (den + 1e-16f);
    short ov[8];
    #pragma unroll
    for (int c = 0; c < 4; c++) {
        ov[2 * c]     = (short)f2bf(acc[c].x * inv);
        ov[2 * c + 1] = (short)f2bf(acc[c].y * inv);
    }
    bf16x8 o8 = {ov[0], ov[1], ov[2], ov[3], ov[4], ov[5], ov[6], ov[7]};
    *(bf16x8*)(Sx + (size_t)node * 512 + hp * 128 + ql * 8) = o8;
}

// ---------------- layer1 projection: h2 = ELU(Sx @ W1 (per head) + b1) --------
__global__ __launch_bounds__(256) void k_proj1(const unsigned short* __restrict__ Sx,
                       const unsigned short* __restrict__ W1t,
                       const float* __restrict__ b1,
                       unsigned short* __restrict__ h2b) {
    int h = blockIdx.x;
    int wave = threadIdx.x >> 6, lane = threadIdx.x & 63;
    int l16 = lane & 15, quad = lane >> 4;
    int m0 = blockIdx.y * 128 + wave * 32;

    f32x4 acc[2][4];
    #pragma unroll
    for (int mt = 0; mt < 2; mt++)
        #pragma unroll
        for (int nt = 0; nt < 4; nt++)
            acc[mt][nt] = (f32x4){0.f, 0.f, 0.f, 0.f};

    int ar0 = min(m0 + l16, NN - 1);
    int ar1 = min(m0 + 16 + l16, NN - 1);
    const unsigned short* a0 = Sx + (size_t)ar0 * 512 + h * 128 + quad * 8;
    const unsigned short* a1 = Sx + (size_t)ar1 * 512 + h * 128 + quad * 8;
    const unsigned short* bp = W1t + (size_t)(h * 64 + l16) * 128 + quad * 8;

    #pragma unroll
    for (int k0 = 0; k0 < 128; k0 += 32) {
        bf16x8 af0 = *(const bf16x8*)(a0 + k0);
        bf16x8 af1 = *(const bf16x8*)(a1 + k0);
        #pragma unroll
        for (int nt = 0; nt < 4; nt++) {
            bf16x8 bf = *(const bf16x8*)(bp + (size_t)nt * 16 * 128 + k0);
            acc[0][nt] = __builtin_amdgcn_mfma_f32_16x16x32_bf16(af0, bf, acc[0][nt], 0, 0, 0);
            acc[1][nt] = __builtin_amdgcn_mfma_f32_16x16x32_bf16(af1, bf, acc[1][nt], 0, 0, 0);
        }
    }

    float bia[4];
    #pragma unroll
    for (int nt = 0; nt < 4; nt++) bia[nt] = b1[h * 64 + nt * 16 + l16];

    #pragma unroll
    for (int mt = 0; mt < 2; mt++)
        #pragma unroll
        for (int reg = 0; reg < 4; reg++) {
            int row = m0 + mt * 16 + quad * 4 + reg;
            if (row < NN) {
                #pragma unroll
                for (int nt = 0; nt < 4; nt++) {
                    float va = acc[mt][nt][reg] + bia[nt];
                    va = (va > 0.f) ? va : __expf(va) - 1.f;   // ELU (natural e!)
                    h2b[(size_t)row * 256 + h * 64 + nt * 16 + l16] = f2bf(va);
                }
            }
        }
}

// ---------------- MFMA bf16 GEMM with fused attention-scalar epilogue ---------
// (layer 2 only) asrc/adst outputs scaled by log2e for exp2-domain k_agg2.
template <int K, int NT, int H>
__global__ __launch_bounds__(256) void gemm_mfma(const unsigned short* __restrict__ A,
                                                 const unsigned short* __restrict__ Bt,
                                                 unsigned short* __restrict__ C,
                                                 const float* __restrict__ avs,
                                                 const float* __restrict__ avd,
                                                 float* __restrict__ asrc,
                                                 float* __restrict__ adst,
                                                 int M, int N) {
    int wave = threadIdx.x >> 6, lane = threadIdx.x & 63;
    int l16 = lane & 15, quad = lane >> 4;
    int m0 = blockIdx.y * 128 + wave * 32;
    int n0 = blockIdx.x * (NT * 16);

    f32x4 acc[2][NT];
    #pragma unroll
    for (int mt = 0; mt < 2; mt++)
        #pragma unroll
        for (int nt = 0; nt < NT; nt++)
            acc[mt][nt] = (f32x4){0.f, 0.f, 0.f, 0.f};

    int ar0 = min(m0 + l16, M - 1);
    int ar1 = min(m0 + 16 + l16, M - 1);
    const unsigned short* a0 = A + (size_t)ar0 * K + quad * 8;
    const unsigned short* a1 = A + (size_t)ar1 * K + quad * 8;
    const unsigned short* bp = Bt + (size_t)(n0 + l16) * K + quad * 8;

    #pragma unroll
    for (int k0 = 0; k0 < K; k0 += 32) {
        bf16x8 af0 = *(const bf16x8*)(a0 + k0);
        bf16x8 af1 = *(const bf16x8*)(a1 + k0);
        #pragma unroll
        for (int nt = 0; nt < NT; nt++) {
            bf16x8 bf = *(const bf16x8*)(bp + (size_t)nt * 16 * K + k0);
            acc[0][nt] = __builtin_amdgcn_mfma_f32_16x16x32_bf16(af0, bf, acc[0][nt], 0, 0, 0);
            acc[1][nt] = __builtin_amdgcn_mfma_f32_16x16x32_bf16(af1, bf, acc[1][nt], 0, 0, 0);
        }
    }

    #pragma unroll
    for (int mt = 0; mt < 2; mt++)
        #pragma unroll
        for (int reg = 0; reg < 4; reg++) {
            int row = m0 + mt * 16 + quad * 4 + reg;
            if (row < M) {
                #pragma unroll
                for (int nt = 0; nt < NT; nt++)
                    C[(size_t)row * N + n0 + nt * 16 + l16] = f2bf(acc[mt][nt][reg]);
            }
        }

    float ws[NT], wd[NT];
    #pragma unroll
    for (int nt = 0; nt < NT; nt++) {
        ws[nt] = avs[n0 + nt * 16 + l16] * LOG2E;
        wd[nt] = avd[n0 + nt * 16 + l16] * LOG2E;
    }
    int hh = n0 >> 6;
    #pragma unroll
    for (int mt = 0; mt < 2; mt++)
        #pragma unroll
        for (int reg = 0; reg < 4; reg++) {
            int row = m0 + mt * 16 + quad * 4 + reg;
            float s1 = 0.f, s2 = 0.f;
            #pragma unroll
            for (int nt = 0; nt < NT; nt++) {
                float c = acc[mt][nt][reg];
                s1 += c * ws[nt];
                s2 += c * wd[nt];
            }
            #pragma unroll
            for (int off = 1; off < 16; off <<= 1) {
                s1 += __shfl_xor(s1, off);
                s2 += __shfl_xor(s2, off);
            }
            if (l16 == 0 && row < M) {
                asrc[row * H + hh] = s1;
                adst[row * H + hh] = s2;
            }
        }
}

// ---------------- layer2 aggregate: full-wave per edge ------------------------
// one wave / node; all 64 lanes process the same edge; lane owns ch
// [lane*2, lane*2+2) (one dword of the 256B row). acc = 1 f32x2; alpha computed
// redundantly per lane (asrc2 table is 200KB -> L2-hit). Zero shuffles; output
// row (512B fp32) written fully coalesced. Slots +4 ahead, payload +2.
__global__ __launch_bounds__(256) void k_agg2(const int* __restrict__ rowptr,
                       const int2* __restrict__ slot, const float* __restrict__ asrc,
                       const float* __restrict__ adst, const float* __restrict__ v,
                       const unsigned short* __restrict__ gb, const float* __restrict__ b2,
                       float* __restrict__ outp) {
    int node = blockIdx.x * 4 + (threadIdx.x >> 6);
    if (node >= NN) return;
    int lane = threadIdx.x & 63;
    int beg = rowptr[node], end = rowptr[node + 1];
    int cnt = end - beg;
    int safe = max(end - 1, 0);
    float ad = adst[node];
    float v0 = v[0], v1 = v[1];
    f32x2 acc = {};
    float den = 0.f, s0 = 0.f, s1 = 0.f;
    const unsigned short* gbq = gb + lane * 2;

    int atA, atB; float asA, asB; unsigned xA, xB;
    int2 rA, rB;
    {
        int iA = min(beg, safe), iB = min(beg + 1, safe);
        int2 sA = slot[iA], sB = slot[iB];
        atA = sA.y; atB = sB.y;
        asA = asrc[sA.x]; asB = asrc[sB.x];
        xA = *(const unsigned*)(gbq + (size_t)(unsigned)sA.x * 128);
        xB = *(const unsigned*)(gbq + (size_t)(unsigned)sB.x * 128);
        rA = slot[min(beg + 2, safe)];
        rB = slot[min(beg + 3, safe)];
    }

#define A2_DO(AT, AS, XR) { \
    f32x2 a = bfpair2((unsigned)(AT)); \
    float al = (AS) + ad + a.x * v0 + a.y * v1; \
    al = (al > 0.f) ? al : 0.2f * al; \
    float e = __builtin_amdgcn_exp2f(al); \
    s0 += a.x; s1 += a.y; den += e; \
    f32x2 E = {e, e}; \
    acc += E * bfpair2(XR); }

    int mend = beg + (cnt & ~1);
    #pragma unroll 1
    for (int p = beg; p < mend; p += 2) {
        A2_DO(atA, asA, xA);                       // edge p
        {
            atA = rA.y;
            asA = asrc[rA.x];
            xA = *(const unsigned*)(gbq + (size_t)(unsigned)rA.x * 128);
            rA = slot[min(p + 4, safe)];
        }
        A2_DO(atB, asB, xB);                       // edge p+1
        {
            atB = rB.y;
            asB = asrc[rB.x];
            xB = *(const unsigned*)(gbq + (size_t)(unsigned)rB.x * 128);
            rB = slot[min(p + 5, safe)];
        }
    }
    if (cnt & 1) { A2_DO(atA, asA, xA); }
#undef A2_DO

    // self-loop epilogue
    float dg = fmaxf((float)cnt, 1.0f);
    float als = asrc[node] + ad + (s0 / dg) * v0 + (s1 / dg) * v1;
    als = (als > 0.f) ? als : 0.2f * als;
    float exs = __builtin_amdgcn_exp2f(als);
    den += exs;

    unsigned r = *(const unsigned*)(gbq + (size_t)node * 128);
    f32x2 E = {exs, exs};
    acc += E * bfpair2(r);

    float inv = 1.f / (den + 1e-16f);
    float2 bb = *(const float2*)(b2 + lane * 2);
    float2 o;
    o.x = acc.x * inv + bb.x;
    o.y = acc.y * inv + bb.y;
    *(float2*)(outp + (size_t)node * 128 + lane * 2) = o;
}

extern "C" void kernel_launch(void* const* d_in, const int* in_sizes, int n_in,
                              void* d_out, int out_size, void* d_ws, size_t ws_size,
                              hipStream_t stream) {
    const float* x     = (const float*)d_in[0];
    const int*   ei    = (const int*)d_in[1];      // int32 on device
    const float* eattr = (const float*)d_in[2];
    const float* W1    = (const float*)d_in[3];
    const float* We1   = (const float*)d_in[4];
    const float* as1   = (const float*)d_in[5];
    const float* ad1   = (const float*)d_in[6];
    const float* ae1   = (const float*)d_in[7];
    const float* b1    = (const float*)d_in[8];
    const float* W2    = (const float*)d_in[9];
    const float* We2   = (const float*)d_in[10];
    const float* as2   = (const float*)d_in[11];
    const float* ad2   = (const float*)d_in[12];
    const float* ae2   = (const float*)d_in[13];
    const float* b2    = (const float*)d_in[14];
    float* out = (float*)d_out;

    // ---- workspace carve ----
    int* idg    = (int*)d_ws;                      // NN
    int* rank   = idg + NN;                        // EE
    int* rowptr = rank + EE;                       // NN+16
    int* bsum   = rowptr + NN + 16;                // 32
    int* boff   = bsum + 32;                       // 32
    int2* slot  = (int2*)(boff + 32);              // EE (8B-aligned)
    float* asrc1 = (float*)(slot + EE);            // 4*NN
    float* adst1 = asrc1 + 4 * NN;                 // 4*NN
    float* asrc2 = adst1 + 4 * NN;                 // NN
    float* adst2 = asrc2 + NN;                     // NN
    float* vbuf  = adst2 + NN;                     // 64
    float* Asd   = vbuf + 64;                      // 1024
    unsigned short* ub = (unsigned short*)(((uintptr_t)(Asd + 1024) + 63) & ~(uintptr_t)63);
    unsigned short* x_bf  = ub;                      // NN*128
    unsigned short* W1t   = x_bf + (size_t)NN * 128; // 256*128
    unsigned short* W2t   = W1t + 32768;             // 128*256
    unsigned short* Sx    = W2t + 32768;             // NN*512
    unsigned short* h2_bf = Sx + (size_t)NN * 512;   // NN*256
    unsigned short* g2_bf = Sx;                      // alias: Sx dead after proj1
    float4* e1   = (float4*)h2_bf;                   // alias: EE*16B = 12.8MB in
                                                     // h2_bf (25.6MB); e1 dead
                                                     // before proj1 writes h2_bf

    hipMemsetAsync(idg, 0, (size_t)NN * sizeof(int), stream);

    // prep (v, Asd, Wt casts, degree hist + rank, x cast) + CSR build
    k_prep<<<9632, 256, 0, stream>>>(We1, ae1, We2, ae2, vbuf, as1, ad1, Asd,
                                     W1, W1t, W2, W2t, ei, idg, rank, x, x_bf);
    k_scan1<<<NB, 512, 0, stream>>>(idg, rowptr, bsum);
    k_scan2<<<1, 64, 0, stream>>>(bsum, boff, rowptr);
    k_scan3<<<NB, 512, 0, stream>>>(rowptr, boff);

    // ---- layer 1 ----  (attn scalars BEFORE scatter; scatter precomputes e1)
    k_attn1<<<(NN + 3) / 4, 256, 0, stream>>>(x_bf, Asd, asrc1, adst1);
    k_scatter<<<(EE + 255) / 256, 256, 0, stream>>>(ei, eattr, rowptr, rank,
                                                    asrc1, adst1, vbuf, slot, e1);
    k_agg1x<<<(NN + 3) / 4, 256, 0, stream>>>(rowptr, slot, (const float*)e1,
                                              asrc1, adst1, vbuf, x_bf, Sx);
    k_proj1<<<dim3(4, (NN + 127) / 128), 256, 0, stream>>>(Sx, W1t, b1, h2_bf);

    // ---- layer 2 ----
    gemm_mfma<256, 8, 1><<<dim3(1, (NN + 127) / 128), 256, 0, stream>>>(
        h2_bf, W2t, g2_bf, as2, ad2, asrc2, adst2, NN, 128);
    k_agg2<<<(NN + 3) / 4, 256, 0, stream>>>(rowptr, slot, asrc2, adst2, vbuf + 8,
                                             g2_bf, b2, out);
}

// Round 7
// 387.478 us; speedup vs baseline: 1.0511x; 1.0511x over previous
//
#include <hip/hip_runtime.h>
#include <hip/hip_bf16.h>

#define NN 50000
#define EE 800000
#define SCAN_B 2048
#define NB ((NN + SCAN_B - 1) / SCAN_B)   // 25 scan blocks
#define LOG2E 1.44269504088896340736f

// NOTE: harness materializes integer inputs as int32 -> edge_index is const int*.
// NOTE (r7): per-channel fp32 scatter atomics (~100M) = ~80us wall. Avoided.
// NOTE (r9): CSR holds real edges only; self-loop handled inline in agg kernels.
// NOTE (r12): aggregate x then project: FETCH 253->139MB confirmed.
// NOTE (r13/r14): 12-group-deep pipelines regress (VGPR 84, occ 28%).
// NOTE (r15): full-wave-per-edge, 2-deep: occ 66% recovered but BW stuck at
//             2.1 TB/s -> occupancy is NOT the lever; in-flight lines/wave is.
//             2-deep x 256B = 8 lines/wave vs r0's ~32.
// NOTE (r16): depth 4 payload + 4 ring (slot->payload->use each 4 edges apart):
//             16 lines/wave at VGPR ~44 (<64 step). Prologue 8 edges ~ ok at
//             mean degree 16.

typedef short bf16x8 __attribute__((ext_vector_type(8)));
typedef float f32x4  __attribute__((ext_vector_type(4)));
typedef float f32x2  __attribute__((ext_vector_type(2)));

__device__ __forceinline__ float bf2f(unsigned short u) {
    return __uint_as_float(((unsigned)u) << 16);
}
__device__ __forceinline__ unsigned short f2bf(float f) {
    unsigned b = __float_as_uint(f);
    b += 0x7fffu + ((b >> 16) & 1u);           // RNE
    return (unsigned short)(b >> 16);
}
__device__ __forceinline__ float2 bfpair(unsigned u) {
    return make_float2(__uint_as_float(u << 16), __uint_as_float(u & 0xffff0000u));
}
__device__ __forceinline__ f32x2 bfpair2(unsigned u) {
    f32x2 r;
    r.x = __uint_as_float(u << 16);
    r.y = __uint_as_float(u & 0xffff0000u);
    return r;
}

// ---------------- fused prep: v-proj + Asd + Wt casts + hist/rank + x cast ----
// v and Asd are pre-scaled by log2e: alphas live in exp2 domain downstream.
__global__ void k_prep(const float* __restrict__ We1, const float* __restrict__ ae1,
                       const float* __restrict__ We2, const float* __restrict__ ae2,
                       float* __restrict__ v,
                       const float* __restrict__ as1, const float* __restrict__ ad1,
                       float* __restrict__ Asd,
                       const float* __restrict__ W1, unsigned short* __restrict__ W1t,
                       const float* __restrict__ W2, unsigned short* __restrict__ W2t,
                       const int* __restrict__ ei, int* __restrict__ idg,
                       int* __restrict__ rank,
                       const float* __restrict__ x, unsigned short* __restrict__ xb) {
    int bid = blockIdx.x, t = threadIdx.x;
    if (bid == 0) {
        if (t < 8) {            // layer1: c=t>>2, h=t&3 -> v[c*4+h]
            int c = t >> 2, h = t & 3;
            float s = 0.f;
            for (int d = 0; d < 64; d++) s += We1[c * 256 + h * 64 + d] * ae1[h * 64 + d];
            v[c * 4 + h] = s * LOG2E;
        } else if (t < 10) {    // layer2: c=t-8 -> v[8+c]
            int c = t - 8;
            float s = 0.f;
            for (int d = 0; d < 128; d++) s += We2[c * 128 + d] * ae2[d];
            v[8 + c] = s * LOG2E;
        }
        // Asd[k*8+j]: j<4 -> sum_c W1[k,j*64+c]*as1[j,c]; j>=4 -> same with ad1
        #pragma unroll 1
        for (int idx = t; idx < 1024; idx += 256) {
            int k = idx >> 3, j = idx & 7;
            const float* a = (j < 4) ? as1 : ad1;
            int h = j & 3;
            float s = 0.f;
            for (int c = 0; c < 64; c++) s += W1[k * 256 + h * 64 + c] * a[h * 64 + c];
            Asd[idx] = s * LOG2E;
        }
    } else if (bid <= 256) {
        int idx = (bid - 1) * 256 + t;
        if (idx < 32768) {                 // W1: 128x256 -> 256x128
            int k = idx >> 8, n = idx & 255;
            W1t[n * 128 + k] = f2bf(W1[idx]);
        } else {                           // W2: 256x128 -> 128x256
            int i = idx - 32768;
            int k = i >> 7, n = i & 127;
            W2t[n * 256 + k] = f2bf(W2[i]);
        }
    } else if (bid <= 256 + 3125) {
        int e = (bid - 257) * 256 + t;
        if (e < EE) rank[e] = atomicAdd(&idg[ei[EE + e]], 1);
    } else {
        int i = (bid - 3382) * 256 + t;
        if (i < NN * 128 / 4) {
            float4 vv = ((const float4*)x)[i];
            ushort4 o;
            o.x = f2bf(vv.x); o.y = f2bf(vv.y); o.z = f2bf(vv.z); o.w = f2bf(vv.w);
            ((ushort4*)xb)[i] = o;
        }
    }
}

// ---------------- CSR build: 3-pass exclusive scan of idg -> rowptr -----------
__global__ void k_scan1(const int* __restrict__ idg, int* __restrict__ rowptr,
                        int* __restrict__ bsum) {
    __shared__ int sh[512];
    int t = threadIdx.x;
    int base = blockIdx.x * SCAN_B + t * 4;
    int v[4]; int s = 0;
    #pragma unroll
    for (int j = 0; j < 4; j++) {
        int i = base + j;
        v[j] = (i < NN) ? idg[i] : 0;
        s += v[j];
    }
    sh[t] = s;
    __syncthreads();
    for (int off = 1; off < 512; off <<= 1) {
        int a = (t >= off) ? sh[t - off] : 0;
        __syncthreads();
        sh[t] += a;
        __syncthreads();
    }
    int run = sh[t] - s;
    #pragma unroll
    for (int j = 0; j < 4; j++) {
        int i = base + j;
        if (i < NN) rowptr[i] = run;
        run += v[j];
    }
    if (t == 511) bsum[blockIdx.x] = sh[511];
}

__global__ void k_scan2(const int* __restrict__ bsum, int* __restrict__ boff,
                        int* __restrict__ rowptr) {
    if (threadIdx.x == 0) {
        int acc = 0;
        for (int b = 0; b < NB; b++) { boff[b] = acc; acc += bsum[b]; }
        rowptr[NN] = acc;      // == EE
    }
}

__global__ void k_scan3(int* __restrict__ rowptr, const int* __restrict__ boff) {
    int t = threadIdx.x;
    int i = blockIdx.x * SCAN_B + t * 4;
    int off = boff[blockIdx.x];
    #pragma unroll
    for (int j = 0; j < 4; j++)
        if (i + j < NN) rowptr[i + j] += off;
}

// ---------------- layer1 attn scalars: asrc/adst = x . Asd (factored) ---------
__global__ __launch_bounds__(256) void k_attn1(const unsigned short* __restrict__ xb,
                       const float* __restrict__ Asd,
                       float* __restrict__ asrc, float* __restrict__ adst) {
    int node = blockIdx.x * 4 + (threadIdx.x >> 6);
    if (node >= NN) return;
    int lane = threadIdx.x & 63;
    unsigned xw = *(const unsigned*)(xb + (size_t)node * 128 + lane * 2);
    float2 xc = bfpair(xw);
    const float4* A4 = (const float4*)Asd;     // [k][8] -> float4 pairs
    float4 s0 = A4[lane * 4 + 0];              // k=2l  src
    float4 d0 = A4[lane * 4 + 1];              // k=2l  dst
    float4 s1 = A4[lane * 4 + 2];              // k=2l+1 src
    float4 d1 = A4[lane * 4 + 3];              // k=2l+1 dst
    float r[8];
    r[0] = xc.x * s0.x + xc.y * s1.x;
    r[1] = xc.x * s0.y + xc.y * s1.y;
    r[2] = xc.x * s0.z + xc.y * s1.z;
    r[3] = xc.x * s0.w + xc.y * s1.w;
    r[4] = xc.x * d0.x + xc.y * d1.x;
    r[5] = xc.x * d0.y + xc.y * d1.y;
    r[6] = xc.x * d0.z + xc.y * d1.z;
    r[7] = xc.x * d0.w + xc.y * d1.w;
    #pragma unroll
    for (int off = 1; off < 64; off <<= 1)
        #pragma unroll
        for (int j = 0; j < 8; j++) r[j] += __shfl_xor(r[j], off);
    if (lane == 0) {
        *(float4*)(asrc + node * 4) = make_float4(r[0], r[1], r[2], r[3]);
        *(float4*)(adst + node * 4) = make_float4(r[4], r[5], r[6], r[7]);
    }
}

// ---------------- scatter + per-edge layer1 exps ------------------------------
// p = rowptr[dst] + rank[e]; slot[p] = {src, bf16 attrs}; e1[p] = exp2 of the 4
// leaky'd head alphas (asrc1[s] + adst1[d] + attr.v, all exp2-domain already).
__global__ void k_scatter(const int* __restrict__ ei, const float* __restrict__ eattr,
                          const int* __restrict__ rowptr, const int* __restrict__ rank,
                          const float* __restrict__ asrc, const float* __restrict__ adst,
                          const float* __restrict__ v,
                          int2* __restrict__ slot, float4* __restrict__ e1) {
    int e = blockIdx.x * blockDim.x + threadIdx.x;
    if (e >= EE) return;
    int s = ei[e], d = ei[EE + e];
    int p = rowptr[d] + rank[e];
    float2 a = ((const float2*)eattr)[e];
    unsigned a0 = f2bf(a.x), a1 = f2bf(a.y);
    slot[p] = make_int2(s, (int)(a0 | (a1 << 16)));
    float4 s4 = *(const float4*)(asrc + s * 4);
    float4 d4 = *(const float4*)(adst + d * 4);
    float al0 = s4.x + d4.x + a.x * v[0] + a.y * v[4];
    float al1 = s4.y + d4.y + a.x * v[1] + a.y * v[5];
    float al2 = s4.z + d4.z + a.x * v[2] + a.y * v[6];
    float al3 = s4.w + d4.w + a.x * v[3] + a.y * v[7];
    al0 = (al0 > 0.f) ? al0 : 0.2f * al0;
    al1 = (al1 > 0.f) ? al1 : 0.2f * al1;
    al2 = (al2 > 0.f) ? al2 : 0.2f * al2;
    al3 = (al3 > 0.f) ? al3 : 0.2f * al3;
    float4 ev;
    ev.x = __builtin_amdgcn_exp2f(al0);
    ev.y = __builtin_amdgcn_exp2f(al1);
    ev.z = __builtin_amdgcn_exp2f(al2);
    ev.w = __builtin_amdgcn_exp2f(al3);
    e1[p] = ev;
}

// ---------------- layer1 aggregate of X: full-wave per edge, 4-deep -----------
// one wave / node; ALL 64 lanes process the same edge. lane = (head hp=lane>>4,
// chan-group ql=lane&15). acc = 8 floats/lane; zero shuffles; coalesced output.
// 4 payload stages (edges p..p+3) + 4-slot ring (p+4..p+7): slot->payload and
// payload->use distances are 4 edges each -> 16 unique lines in flight/wave.
__global__ __launch_bounds__(256) void k_agg1x(const int* __restrict__ rowptr,
                       const int2* __restrict__ slot, const float* __restrict__ e1v,
                       const float* __restrict__ asrc, const float* __restrict__ adst,
                       const float* __restrict__ v,
                       const unsigned short* __restrict__ xb,
                       unsigned short* __restrict__ Sx) {
    int node = blockIdx.x * 4 + (threadIdx.x >> 6);
    if (node >= NN) return;
    int lane = threadIdx.x & 63;
    int hp = lane >> 4;          // head
    int ql = lane & 15;          // chan-group: owns ch [ql*8, ql*8+8) of head hp
    int beg = rowptr[node], end = rowptr[node + 1];
    int cnt = end - beg;
    int safe = max(end - 1, 0);
    const unsigned short* xbq = xb + ql * 8;

    f32x2 acc[4] = {};
    float den = 0.f, s0 = 0.f, s1 = 0.f;

    int atA, atB, atC, atD;
    float eA, eB, eC, eD;
    uint4 xA, xB, xC, xD;
    int2 rA, rB, rC, rD;
    {
        int iA = min(beg, safe),     iB = min(beg + 1, safe);
        int iC = min(beg + 2, safe), iD = min(beg + 3, safe);
        int2 sA = slot[iA], sB = slot[iB], sC = slot[iC], sD = slot[iD];
        atA = sA.y; atB = sB.y; atC = sC.y; atD = sD.y;
        eA = e1v[iA * 4 + hp]; eB = e1v[iB * 4 + hp];
        eC = e1v[iC * 4 + hp]; eD = e1v[iD * 4 + hp];
        xA = *(const uint4*)(xbq + (size_t)(unsigned)sA.x * 128);
        xB = *(const uint4*)(xbq + (size_t)(unsigned)sB.x * 128);
        xC = *(const uint4*)(xbq + (size_t)(unsigned)sC.x * 128);
        xD = *(const uint4*)(xbq + (size_t)(unsigned)sD.x * 128);
        rA = slot[min(beg + 4, safe)];
        rB = slot[min(beg + 5, safe)];
        rC = slot[min(beg + 6, safe)];
        rD = slot[min(beg + 7, safe)];
    }

#define A1_DO(AT, EV, XR) { \
    f32x2 a = bfpair2((unsigned)(AT)); \
    s0 += a.x; s1 += a.y; den += (EV); \
    f32x2 E = {(EV), (EV)}; \
    acc[0] += E * bfpair2((XR).x); acc[1] += E * bfpair2((XR).y); \
    acc[2] += E * bfpair2((XR).z); acc[3] += E * bfpair2((XR).w); }
#define A1_RELOAD(K, PP) { \
    int i = min((PP), safe); \
    at##K = r##K.y; \
    e##K = e1v[i * 4 + hp]; \
    x##K = *(const uint4*)(xbq + (size_t)(unsigned)r##K.x * 128); \
    r##K = slot[min((PP) + 4, safe)]; }

    int mend = beg + (cnt & ~3);
    #pragma unroll 1
    for (int p = beg; p < mend; p += 4) {
        A1_DO(atA, eA, xA); A1_RELOAD(A, p + 4);
        A1_DO(atB, eB, xB); A1_RELOAD(B, p + 5);
        A1_DO(atC, eC, xC); A1_RELOAD(C, p + 6);
        A1_DO(atD, eD, xD); A1_RELOAD(D, p + 7);
    }
    int tail = cnt & 3;
    if (tail > 0) { A1_DO(atA, eA, xA); }
    if (tail > 1) { A1_DO(atB, eB, xB); }
    if (tail > 2) { A1_DO(atC, eC, xC); }
#undef A1_DO
#undef A1_RELOAD

    // self-loop: mean attrs over real edges (0 if none)
    float dg = fmaxf((float)cnt, 1.0f);
    float als = asrc[node * 4 + hp] + adst[node * 4 + hp]
              + (s0 / dg) * v[hp] + (s1 / dg) * v[4 + hp];
    als = (als > 0.f) ? als : 0.2f * als;
    float exs = __builtin_amdgcn_exp2f(als);
    den += exs;

    uint4 r = *(const uint4*)(xbq + (size_t)node * 128);
    f32x2 E = {exs, exs};
    acc[0] += E * bfpair2(r.x); acc[1] += E * bfpair2(r.y);
    acc[2] += E * bfpair2(r.z); acc[3] += E * bfpair2(r.w);

    float inv = 1.f / (den + 1e-16f);
    short ov[8];
    #pragma unroll
    for (int c = 0; c < 4; c++) {
        ov[2 * c]     = (short)f2bf(acc[c].x * inv);
        ov[2 * c + 1] = (short)f2bf(acc[c].y * inv);
    }
    bf16x8 o8 = {ov[0], ov[1], ov[2], ov[3], ov[4], ov[5], ov[6], ov[7]};
    *(bf16x8*)(Sx + (size_t)node * 512 + hp * 128 + ql * 8) = o8;
}

// ---------------- layer1 projection: h2 = ELU(Sx @ W1 (per head) + b1) --------
__global__ __launch_bounds__(256) void k_proj1(const unsigned short* __restrict__ Sx,
                       const unsigned short* __restrict__ W1t,
                       const float* __restrict__ b1,
                       unsigned short* __restrict__ h2b) {
    int h = blockIdx.x;
    int wave = threadIdx.x >> 6, lane = threadIdx.x & 63;
    int l16 = lane & 15, quad = lane >> 4;
    int m0 = blockIdx.y * 128 + wave * 32;

    f32x4 acc[2][4];
    #pragma unroll
    for (int mt = 0; mt < 2; mt++)
        #pragma unroll
        for (int nt = 0; nt < 4; nt++)
            acc[mt][nt] = (f32x4){0.f, 0.f, 0.f, 0.f};

    int ar0 = min(m0 + l16, NN - 1);
    int ar1 = min(m0 + 16 + l16, NN - 1);
    const unsigned short* a0 = Sx + (size_t)ar0 * 512 + h * 128 + quad * 8;
    const unsigned short* a1 = Sx + (size_t)ar1 * 512 + h * 128 + quad * 8;
    const unsigned short* bp = W1t + (size_t)(h * 64 + l16) * 128 + quad * 8;

    #pragma unroll
    for (int k0 = 0; k0 < 128; k0 += 32) {
        bf16x8 af0 = *(const bf16x8*)(a0 + k0);
        bf16x8 af1 = *(const bf16x8*)(a1 + k0);
        #pragma unroll
        for (int nt = 0; nt < 4; nt++) {
            bf16x8 bf = *(const bf16x8*)(bp + (size_t)nt * 16 * 128 + k0);
            acc[0][nt] = __builtin_amdgcn_mfma_f32_16x16x32_bf16(af0, bf, acc[0][nt], 0, 0, 0);
            acc[1][nt] = __builtin_amdgcn_mfma_f32_16x16x32_bf16(af1, bf, acc[1][nt], 0, 0, 0);
        }
    }

    float bia[4];
    #pragma unroll
    for (int nt = 0; nt < 4; nt++) bia[nt] = b1[h * 64 + nt * 16 + l16];

    #pragma unroll
    for (int mt = 0; mt < 2; mt++)
        #pragma unroll
        for (int reg = 0; reg < 4; reg++) {
            int row = m0 + mt * 16 + quad * 4 + reg;
            if (row < NN) {
                #pragma unroll
                for (int nt = 0; nt < 4; nt++) {
                    float va = acc[mt][nt][reg] + bia[nt];
                    va = (va > 0.f) ? va : __expf(va) - 1.f;   // ELU (natural e!)
                    h2b[(size_t)row * 256 + h * 64 + nt * 16 + l16] = f2bf(va);
                }
            }
        }
}

// ---------------- MFMA bf16 GEMM with fused attention-scalar epilogue ---------
// (layer 2 only) asrc/adst outputs scaled by log2e for exp2-domain k_agg2.
template <int K, int NT, int H>
__global__ __launch_bounds__(256) void gemm_mfma(const unsigned short* __restrict__ A,
                                                 const unsigned short* __restrict__ Bt,
                                                 unsigned short* __restrict__ C,
                                                 const float* __restrict__ avs,
                                                 const float* __restrict__ avd,
                                                 float* __restrict__ asrc,
                                                 float* __restrict__ adst,
                                                 int M, int N) {
    int wave = threadIdx.x >> 6, lane = threadIdx.x & 63;
    int l16 = lane & 15, quad = lane >> 4;
    int m0 = blockIdx.y * 128 + wave * 32;
    int n0 = blockIdx.x * (NT * 16);

    f32x4 acc[2][NT];
    #pragma unroll
    for (int mt = 0; mt < 2; mt++)
        #pragma unroll
        for (int nt = 0; nt < NT; nt++)
            acc[mt][nt] = (f32x4){0.f, 0.f, 0.f, 0.f};

    int ar0 = min(m0 + l16, M - 1);
    int ar1 = min(m0 + 16 + l16, M - 1);
    const unsigned short* a0 = A + (size_t)ar0 * K + quad * 8;
    const unsigned short* a1 = A + (size_t)ar1 * K + quad * 8;
    const unsigned short* bp = Bt + (size_t)(n0 + l16) * K + quad * 8;

    #pragma unroll
    for (int k0 = 0; k0 < K; k0 += 32) {
        bf16x8 af0 = *(const bf16x8*)(a0 + k0);
        bf16x8 af1 = *(const bf16x8*)(a1 + k0);
        #pragma unroll
        for (int nt = 0; nt < NT; nt++) {
            bf16x8 bf = *(const bf16x8*)(bp + (size_t)nt * 16 * K + k0);
            acc[0][nt] = __builtin_amdgcn_mfma_f32_16x16x32_bf16(af0, bf, acc[0][nt], 0, 0, 0);
            acc[1][nt] = __builtin_amdgcn_mfma_f32_16x16x32_bf16(af1, bf, acc[1][nt], 0, 0, 0);
        }
    }

    #pragma unroll
    for (int mt = 0; mt < 2; mt++)
        #pragma unroll
        for (int reg = 0; reg < 4; reg++) {
            int row = m0 + mt * 16 + quad * 4 + reg;
            if (row < M) {
                #pragma unroll
                for (int nt = 0; nt < NT; nt++)
                    C[(size_t)row * N + n0 + nt * 16 + l16] = f2bf(acc[mt][nt][reg]);
            }
        }

    float ws[NT], wd[NT];
    #pragma unroll
    for (int nt = 0; nt < NT; nt++) {
        ws[nt] = avs[n0 + nt * 16 + l16] * LOG2E;
        wd[nt] = avd[n0 + nt * 16 + l16] * LOG2E;
    }
    int hh = n0 >> 6;
    #pragma unroll
    for (int mt = 0; mt < 2; mt++)
        #pragma unroll
        for (int reg = 0; reg < 4; reg++) {
            int row = m0 + mt * 16 + quad * 4 + reg;
            float s1 = 0.f, s2 = 0.f;
            #pragma unroll
            for (int nt = 0; nt < NT; nt++) {
                float c = acc[mt][nt][reg];
                s1 += c * ws[nt];
                s2 += c * wd[nt];
            }
            #pragma unroll
            for (int off = 1; off < 16; off <<= 1) {
                s1 += __shfl_xor(s1, off);
                s2 += __shfl_xor(s2, off);
            }
            if (l16 == 0 && row < M) {
                asrc[row * H + hh] = s1;
                adst[row * H + hh] = s2;
            }
        }
}

// ---------------- layer2 aggregate: full-wave per edge, 4-deep ----------------
// one wave / node; all 64 lanes same edge; lane owns ch [lane*2, lane*2+2).
// 4 payload stages + 4-slot ring; zero shuffles; coalesced output.
__global__ __launch_bounds__(256) void k_agg2(const int* __restrict__ rowptr,
                       const int2* __restrict__ slot, const float* __restrict__ asrc,
                       const float* __restrict__ adst, const float* __restrict__ v,
                       const unsigned short* __restrict__ gb, const float* __restrict__ b2,
                       float* __restrict__ outp) {
    int node = blockIdx.x * 4 + (threadIdx.x >> 6);
    if (node >= NN) return;
    int lane = threadIdx.x & 63;
    int beg = rowptr[node], end = rowptr[node + 1];
    int cnt = end - beg;
    int safe = max(end - 1, 0);
    float ad = adst[node];
    float v0 = v[0], v1 = v[1];
    f32x2 acc = {};
    float den = 0.f, s0 = 0.f, s1 = 0.f;
    const unsigned short* gbq = gb + lane * 2;

    int atA, atB, atC, atD;
    float asA, asB, asC, asD;
    unsigned xA, xB, xC, xD;
    int2 rA, rB, rC, rD;
    {
        int iA = min(beg, safe),     iB = min(beg + 1, safe);
        int iC = min(beg + 2, safe), iD = min(beg + 3, safe);
        int2 sA = slot[iA], sB = slot[iB], sC = slot[iC], sD = slot[iD];
        atA = sA.y; atB = sB.y; atC = sC.y; atD = sD.y;
        asA = asrc[sA.x]; asB = asrc[sB.x]; asC = asrc[sC.x]; asD = asrc[sD.x];
        xA = *(const unsigned*)(gbq + (size_t)(unsigned)sA.x * 128);
        xB = *(const unsigned*)(gbq + (size_t)(unsigned)sB.x * 128);
        xC = *(const unsigned*)(gbq + (size_t)(unsigned)sC.x * 128);
        xD = *(const unsigned*)(gbq + (size_t)(unsigned)sD.x * 128);
        rA = slot[min(beg + 4, safe)];
        rB = slot[min(beg + 5, safe)];
        rC = slot[min(beg + 6, safe)];
        rD = slot[min(beg + 7, safe)];
    }

#define A2_DO(AT, AS, XR) { \
    f32x2 a = bfpair2((unsigned)(AT)); \
    float al = (AS) + ad + a.x * v0 + a.y * v1; \
    al = (al > 0.f) ? al : 0.2f * al; \
    float e = __builtin_amdgcn_exp2f(al); \
    s0 += a.x; s1 += a.y; den += e; \
    f32x2 E = {e, e}; \
    acc += E * bfpair2(XR); }
#define A2_RELOAD(K, PP) { \
    at##K = r##K.y; \
    as##K = asrc[r##K.x]; \
    x##K = *(const unsigned*)(gbq + (size_t)(unsigned)r##K.x * 128); \
    r##K = slot[min((PP) + 4, safe)]; }

    int mend = beg + (cnt & ~3);
    #pragma unroll 1
    for (int p = beg; p < mend; p += 4) {
        A2_DO(atA, asA, xA); A2_RELOAD(A, p + 4);
        A2_DO(atB, asB, xB); A2_RELOAD(B, p + 5);
        A2_DO(atC, asC, xC); A2_RELOAD(C, p + 6);
        A2_DO(atD, asD, xD); A2_RELOAD(D, p + 7);
    }
    int tail = cnt & 3;
    if (tail > 0) { A2_DO(atA, asA, xA); }
    if (tail > 1) { A2_DO(atB, asB, xB); }
    if (tail > 2) { A2_DO(atC, asC, xC); }
#undef A2_DO
#undef A2_RELOAD

    // self-loop epilogue
    float dg = fmaxf((float)cnt, 1.0f);
    float als = asrc[node] + ad + (s0 / dg) * v0 + (s1 / dg) * v1;
    als = (als > 0.f) ? als : 0.2f * als;
    float exs = __builtin_amdgcn_exp2f(als);
    den += exs;

    unsigned r = *(const unsigned*)(gbq + (size_t)node * 128);
    f32x2 E = {exs, exs};
    acc += E * bfpair2(r);

    float inv = 1.f / (den + 1e-16f);
    float2 bb = *(const float2*)(b2 + lane * 2);
    float2 o;
    o.x = acc.x * inv + bb.x;
    o.y = acc.y * inv + bb.y;
    *(float2*)(outp + (size_t)node * 128 + lane * 2) = o;
}

extern "C" void kernel_launch(void* const* d_in, const int* in_sizes, int n_in,
                              void* d_out, int out_size, void* d_ws, size_t ws_size,
                              hipStream_t stream) {
    const float* x     = (const float*)d_in[0];
    const int*   ei    = (const int*)d_in[1];      // int32 on device
    const float* eattr = (const float*)d_in[2];
    const float* W1    = (const float*)d_in[3];
    const float* We1   = (const float*)d_in[4];
    const float* as1   = (const float*)d_in[5];
    const float* ad1   = (const float*)d_in[6];
    const float* ae1   = (const float*)d_in[7];
    const float* b1    = (const float*)d_in[8];
    const float* W2    = (const float*)d_in[9];
    const float* We2   = (const float*)d_in[10];
    const float* as2   = (const float*)d_in[11];
    const float* ad2   = (const float*)d_in[12];
    const float* ae2   = (const float*)d_in[13];
    const float* b2    = (const float*)d_in[14];
    float* out = (float*)d_out;

    // ---- workspace carve ----
    int* idg    = (int*)d_ws;                      // NN
    int* rank   = idg + NN;                        // EE
    int* rowptr = rank + EE;                       // NN+16
    int* bsum   = rowptr + NN + 16;                // 32
    int* boff   = bsum + 32;                       // 32
    int2* slot  = (int2*)(boff + 32);              // EE (8B-aligned)
    float* asrc1 = (float*)(slot + EE);            // 4*NN
    float* adst1 = asrc1 + 4 * NN;                 // 4*NN
    float* asrc2 = adst1 + 4 * NN;                 // NN
    float* adst2 = asrc2 + NN;                     // NN
    float* vbuf  = adst2 + NN;                     // 64
    float* Asd   = vbuf + 64;                      // 1024
    unsigned short* ub = (unsigned short*)(((uintptr_t)(Asd + 1024) + 63) & ~(uintptr_t)63);
    unsigned short* x_bf  = ub;                      // NN*128
    unsigned short* W1t   = x_bf + (size_t)NN * 128; // 256*128
    unsigned short* W2t   = W1t + 32768;             // 128*256
    unsigned short* Sx    = W2t + 32768;             // NN*512
    unsigned short* h2_bf = Sx + (size_t)NN * 512;   // NN*256
    unsigned short* g2_bf = Sx;                      // alias: Sx dead after proj1
    float4* e1   = (float4*)h2_bf;                   // alias: EE*16B = 12.8MB in
                                                     // h2_bf (25.6MB); e1 dead
                                                     // before proj1 writes h2_bf

    hipMemsetAsync(idg, 0, (size_t)NN * sizeof(int), stream);

    // prep (v, Asd, Wt casts, degree hist + rank, x cast) + CSR build
    k_prep<<<9632, 256, 0, stream>>>(We1, ae1, We2, ae2, vbuf, as1, ad1, Asd,
                                     W1, W1t, W2, W2t, ei, idg, rank, x, x_bf);
    k_scan1<<<NB, 512, 0, stream>>>(idg, rowptr, bsum);
    k_scan2<<<1, 64, 0, stream>>>(bsum, boff, rowptr);
    k_scan3<<<NB, 512, 0, stream>>>(rowptr, boff);

    // ---- layer 1 ----  (attn scalars BEFORE scatter; scatter precomputes e1)
    k_attn1<<<(NN + 3) / 4, 256, 0, stream>>>(x_bf, Asd, asrc1, adst1);
    k_scatter<<<(EE + 255) / 256, 256, 0, stream>>>(ei, eattr, rowptr, rank,
                                                    asrc1, adst1, vbuf, slot, e1);
    k_agg1x<<<(NN + 3) / 4, 256, 0, stream>>>(rowptr, slot, (const float*)e1,
                                              asrc1, adst1, vbuf, x_bf, Sx);
    k_proj1<<<dim3(4, (NN + 127) / 128), 256, 0, stream>>>(Sx, W1t, b1, h2_bf);

    // ---- layer 2 ----
    gemm_mfma<256, 8, 1><<<dim3(1, (NN + 127) / 128), 256, 0, stream>>>(
        h2_bf, W2t, g2_bf, as2, ad2, asrc2, adst2, NN, 128);
    k_agg2<<<(NN + 3) / 4, 256, 0, stream>>>(rowptr, slot, asrc2, adst2, vbuf + 8,
                                             g2_bf, b2, out);
}

// Round 8
// 331.534 us; speedup vs baseline: 1.2284x; 1.1687x over previous
//
#include <hip/hip_runtime.h>
#include <hip/hip_bf16.h>

#define NN 50000
#define EE 800000
#define SCAN_B 2048
#define NB ((NN + SCAN_B - 1) / SCAN_B)   // 25 scan blocks
#define LOG2E 1.44269504088896340736f

// NOTE: harness materializes integer inputs as int32 -> edge_index is const int*.
// NOTE (r7): fp32 scatter atomics = ~80us atomic-latency wall. Avoided.
// NOTE (r9): CSR holds real edges only; self-loop handled inline in agg kernels.
// NOTE (r10-r16): EVERY agg schedule (shuffle-batch / half-wave / quarter-wave /
//   full-wave, depth 2-12, 256B or 512B rows) pins at 77-88us. Invariant:
//   800K edges / 77us = 10.4G random bursts/s beyond-L2 = the fabric wall.
//   Bytes, occupancy, depth don't move it. Aggs have a ~155us combined floor.
//   r12's aggregate-x restructure LOST time by adding kernels around the wall.
// NOTE (r17): revert to r11 structure (best: 327.7us). Cuts: gemm1 reads fp32 x
//   directly (in-register bf16 pack, drops 38MB cast pass), exp2-domain softmax.

typedef short bf16x8 __attribute__((ext_vector_type(8)));
typedef float f32x4  __attribute__((ext_vector_type(4)));

__device__ __forceinline__ float bf2f(unsigned short u) {
    return __uint_as_float(((unsigned)u) << 16);
}
__device__ __forceinline__ unsigned short f2bf(float f) {
    unsigned b = __float_as_uint(f);
    b += 0x7fffu + ((b >> 16) & 1u);           // RNE
    return (unsigned short)(b >> 16);
}
// dword holding two bf16 -> two floats (1 shl + 1 and)
__device__ __forceinline__ float2 bfpair(unsigned u) {
    return make_float2(__uint_as_float(u << 16), __uint_as_float(u & 0xffff0000u));
}

// A-fragment loaders for the GEMM: bf16 direct, or fp32 packed in-register (RNE,
// bit-identical to a separate cast pass).
__device__ __forceinline__ bf16x8 load_a8(const unsigned short* p) {
    return *(const bf16x8*)p;
}
__device__ __forceinline__ bf16x8 load_a8(const float* p) {
    float4 u = *(const float4*)p;
    float4 w = *(const float4*)(p + 4);
    bf16x8 r;
    r[0] = (short)f2bf(u.x); r[1] = (short)f2bf(u.y);
    r[2] = (short)f2bf(u.z); r[3] = (short)f2bf(u.w);
    r[4] = (short)f2bf(w.x); r[5] = (short)f2bf(w.y);
    r[6] = (short)f2bf(w.z); r[7] = (short)f2bf(w.w);
    return r;
}

// ---------------- fused prep: v-projection + Wt casts + hist/rank -------------
// block 0: v ; blocks [1,256]: Wt ; [257,3381]: hist+rank
// v is pre-scaled by log2e (alphas live in exp2 domain downstream).
__global__ void k_prep(const float* __restrict__ We1, const float* __restrict__ ae1,
                       const float* __restrict__ We2, const float* __restrict__ ae2,
                       float* __restrict__ v,
                       const float* __restrict__ W1, unsigned short* __restrict__ W1t,
                       const float* __restrict__ W2, unsigned short* __restrict__ W2t,
                       const int* __restrict__ ei, int* __restrict__ idg,
                       int* __restrict__ rank) {
    int bid = blockIdx.x, t = threadIdx.x;
    if (bid == 0) {
        if (t < 8) {            // layer1: c=t>>2, h=t&3 -> v[c*4+h]
            int c = t >> 2, h = t & 3;
            float s = 0.f;
            for (int d = 0; d < 64; d++) s += We1[c * 256 + h * 64 + d] * ae1[h * 64 + d];
            v[c * 4 + h] = s * LOG2E;
        } else if (t < 10) {    // layer2: c=t-8 -> v[8+c]
            int c = t - 8;
            float s = 0.f;
            for (int d = 0; d < 128; d++) s += We2[c * 128 + d] * ae2[d];
            v[8 + c] = s * LOG2E;
        }
    } else if (bid <= 256) {
        int idx = (bid - 1) * 256 + t;
        if (idx < 32768) {                 // W1: 128x256 -> 256x128
            int k = idx >> 8, n = idx & 255;
            W1t[n * 128 + k] = f2bf(W1[idx]);
        } else {                           // W2: 256x128 -> 128x256
            int i = idx - 32768;
            int k = i >> 7, n = i & 127;
            W2t[n * 256 + k] = f2bf(W2[i]);
        }
    } else {
        int e = (bid - 257) * 256 + t;
        if (e < EE) rank[e] = atomicAdd(&idg[ei[EE + e]], 1);
    }
}

// ---------------- CSR build: 3-pass exclusive scan of idg -> rowptr -----------
__global__ void k_scan1(const int* __restrict__ idg, int* __restrict__ rowptr,
                        int* __restrict__ bsum) {
    __shared__ int sh[512];
    int t = threadIdx.x;
    int base = blockIdx.x * SCAN_B + t * 4;
    int v[4]; int s = 0;
    #pragma unroll
    for (int j = 0; j < 4; j++) {
        int i = base + j;
        v[j] = (i < NN) ? idg[i] : 0;
        s += v[j];
    }
    sh[t] = s;
    __syncthreads();
    for (int off = 1; off < 512; off <<= 1) {
        int a = (t >= off) ? sh[t - off] : 0;
        __syncthreads();
        sh[t] += a;
        __syncthreads();
    }
    int run = sh[t] - s;
    #pragma unroll
    for (int j = 0; j < 4; j++) {
        int i = base + j;
        if (i < NN) rowptr[i] = run;
        run += v[j];
    }
    if (t == 511) bsum[blockIdx.x] = sh[511];
}

__global__ void k_scan2(const int* __restrict__ bsum, int* __restrict__ boff,
                        int* __restrict__ rowptr) {
    if (threadIdx.x == 0) {
        int acc = 0;
        for (int b = 0; b < NB; b++) { boff[b] = acc; acc += bsum[b]; }
        rowptr[NN] = acc;      // == EE
    }
}

__global__ void k_scan3(int* __restrict__ rowptr, const int* __restrict__ boff) {
    int t = threadIdx.x;
    int i = blockIdx.x * SCAN_B + t * 4;
    int off = boff[blockIdx.x];
    #pragma unroll
    for (int j = 0; j < 4; j++)
        if (i + j < NN) rowptr[i + j] += off;
}

// ---------------- atomic-free scatter: p = rowptr[dst] + rank[e] --------------
__global__ void k_scatter(const int* __restrict__ ei, const float* __restrict__ eattr,
                          const int* __restrict__ rowptr, const int* __restrict__ rank,
                          int2* __restrict__ slot) {
    int e = blockIdx.x * blockDim.x + threadIdx.x;
    if (e >= EE) return;
    int s = ei[e], d = ei[EE + e];
    int p = rowptr[d] + rank[e];
    float2 a = ((const float2*)eattr)[e];
    unsigned a0 = f2bf(a.x), a1 = f2bf(a.y);
    slot[p] = make_int2(s, (int)(a0 | (a1 << 16)));
}

// ---------------- MFMA bf16 GEMM with fused attention-scalar epilogue ---------
// C[M,N] = A[M,K] @ Bt[N,K]^T (bf16 out). Per block: 128 rows x NT*16 cols.
// A may be bf16 (ushort) or fp32 (in-register RNE pack, identical values).
// asrc/adst epilogue outputs are scaled by log2e (consumed in exp2 domain).
template <int K, int NT, int H, typename AT>
__global__ __launch_bounds__(256) void gemm_mfma(const AT* __restrict__ A,
                                                 const unsigned short* __restrict__ Bt,
                                                 unsigned short* __restrict__ C,
                                                 const float* __restrict__ avs,
                                                 const float* __restrict__ avd,
                                                 float* __restrict__ asrc,
                                                 float* __restrict__ adst,
                                                 int M, int N) {
    int wave = threadIdx.x >> 6, lane = threadIdx.x & 63;
    int l16 = lane & 15, quad = lane >> 4;
    int m0 = blockIdx.y * 128 + wave * 32;
    int n0 = blockIdx.x * (NT * 16);

    f32x4 acc[2][NT];
    #pragma unroll
    for (int mt = 0; mt < 2; mt++)
        #pragma unroll
        for (int nt = 0; nt < NT; nt++)
            acc[mt][nt] = (f32x4){0.f, 0.f, 0.f, 0.f};

    int ar0 = min(m0 + l16, M - 1);
    int ar1 = min(m0 + 16 + l16, M - 1);
    const AT* a0 = A + (size_t)ar0 * K + quad * 8;
    const AT* a1 = A + (size_t)ar1 * K + quad * 8;
    const unsigned short* bp = Bt + (size_t)(n0 + l16) * K + quad * 8;

    #pragma unroll
    for (int k0 = 0; k0 < K; k0 += 32) {
        bf16x8 af0 = load_a8(a0 + k0);
        bf16x8 af1 = load_a8(a1 + k0);
        #pragma unroll
        for (int nt = 0; nt < NT; nt++) {
            bf16x8 bf = *(const bf16x8*)(bp + (size_t)nt * 16 * K + k0);
            acc[0][nt] = __builtin_amdgcn_mfma_f32_16x16x32_bf16(af0, bf, acc[0][nt], 0, 0, 0);
            acc[1][nt] = __builtin_amdgcn_mfma_f32_16x16x32_bf16(af1, bf, acc[1][nt], 0, 0, 0);
        }
    }

    // C store. C/D layout: col = l16, row = quad*4 + reg
    #pragma unroll
    for (int mt = 0; mt < 2; mt++)
        #pragma unroll
        for (int reg = 0; reg < 4; reg++) {
            int row = m0 + mt * 16 + quad * 4 + reg;
            if (row < M) {
                #pragma unroll
                for (int nt = 0; nt < NT; nt++)
                    C[(size_t)row * N + n0 + nt * 16 + l16] = f2bf(acc[mt][nt][reg]);
            }
        }

    // fused attn scalars: asrc/adst[row, head] from fp32 acc (log2e-scaled)
    float ws[NT], wd[NT];
    #pragma unroll
    for (int nt = 0; nt < NT; nt++) {
        ws[nt] = avs[n0 + nt * 16 + l16] * LOG2E;
        wd[nt] = avd[n0 + nt * 16 + l16] * LOG2E;
    }
    int hh = n0 >> 6;          // head index (layer1: blockIdx.x; layer2: 0)
    #pragma unroll
    for (int mt = 0; mt < 2; mt++)
        #pragma unroll
        for (int reg = 0; reg < 4; reg++) {
            int row = m0 + mt * 16 + quad * 4 + reg;
            float s1 = 0.f, s2 = 0.f;
            #pragma unroll
            for (int nt = 0; nt < NT; nt++) {
                float c = acc[mt][nt][reg];
                s1 += c * ws[nt];
                s2 += c * wd[nt];
            }
            #pragma unroll
            for (int off = 1; off < 16; off <<= 1) {
                s1 += __shfl_xor(s1, off);
                s2 += __shfl_xor(s2, off);
            }
            if (l16 == 0 && row < M) {
                asrc[row * H + hh] = s1;
                adst[row * H + hh] = s2;
            }
        }
}

// ---------------- layer1 fused softmax+aggregate+bias+ELU ---------------------
// one wave / node; HALF-wave (32 lanes) per edge, 2 edges per wave iteration.
// Lane hl owns channels [hl*8, hl*8+8) -> exactly one head (hl>>3): one alpha
// chain + one exp per lane per edge. Branchless 2-stage rotating slot prefetch
// (clamped index). exp2-domain alphas. No main-loop shuffles.
__global__ __launch_bounds__(256) void k_agg1(const int* __restrict__ rowptr,
                       const int2* __restrict__ slot, const float* __restrict__ asrc,
                       const float* __restrict__ adst, const float* __restrict__ v,
                       const unsigned short* __restrict__ hb, const float* __restrict__ b1,
                       unsigned short* __restrict__ h2b) {
    int node = blockIdx.x * 4 + (threadIdx.x >> 6);
    if (node >= NN) return;
    int lane = threadIdx.x & 63;
    int h2 = lane >> 5;          // which edge of the pair
    int hl = lane & 31;          // channel-lane: owns ch [hl*8, hl*8+8)
    int hd = hl >> 3;            // head owning this lane's channels
    int beg = rowptr[node], end = rowptr[node + 1];
    float pd = adst[node * 4 + hd];
    float vh0 = v[hd], vh1 = v[4 + hd];
    float acc[8] = {};
    float den = 0.f, s0 = 0.f, s1 = 0.f;
    const unsigned short* hbq = hb + hl * 8;

    int cnt = end - beg;
    int safeLast = max(end - 1, 0);
    int mend = beg + (cnt & ~1);

    int2 sl0 = slot[min(beg + h2, safeLast)];
    int2 sl1 = slot[min(beg + 2 + h2, safeLast)];

    auto body = [&](int2 cur) {
        int s = cur.x;
        float2 a = bfpair((unsigned)cur.y);
        float al = asrc[s * 4 + hd] + pd + a.x * vh0 + a.y * vh1;
        al = (al > 0.f) ? al : 0.2f * al;
        float e = __builtin_amdgcn_exp2f(al);
        s0 += a.x; s1 += a.y; den += e;
        uint4 r = *(const uint4*)(hbq + (size_t)s * 256);
        float2 p;
        p = bfpair(r.x); acc[0] += e * p.x; acc[1] += e * p.y;
        p = bfpair(r.y); acc[2] += e * p.x; acc[3] += e * p.y;
        p = bfpair(r.z); acc[4] += e * p.x; acc[5] += e * p.y;
        p = bfpair(r.w); acc[6] += e * p.x; acc[7] += e * p.y;
    };

    #pragma unroll 2
    for (int pb = beg; pb < mend; pb += 2) {
        int2 cur = sl0;
        sl0 = sl1;
        sl1 = slot[min(pb + 4 + h2, safeLast)];
        body(cur);
    }
    if (h2 == 0 && mend < end) body(sl0);   // odd tail: half 0 only

    // cross-half reductions (only shuffles in the kernel)
    #pragma unroll
    for (int k = 0; k < 8; k++) acc[k] += __shfl_down(acc[k], 32);
    den += __shfl_xor(den, 32);
    s0  += __shfl_xor(s0, 32);
    s1  += __shfl_xor(s1, 32);

    // self-loop: mean attrs over real edges (0 if none)
    float dg = fmaxf((float)cnt, 1.0f);
    float als = asrc[node * 4 + hd] + pd + (s0 / dg) * vh0 + (s1 / dg) * vh1;
    als = (als > 0.f) ? als : 0.2f * als;
    float exs = __builtin_amdgcn_exp2f(als);
    den += exs;

    if (h2 == 0) {
        uint4 r = *(const uint4*)(hbq + (size_t)node * 256);
        float2 p;
        p = bfpair(r.x); acc[0] += exs * p.x; acc[1] += exs * p.y;
        p = bfpair(r.y); acc[2] += exs * p.x; acc[3] += exs * p.y;
        p = bfpair(r.z); acc[4] += exs * p.x; acc[5] += exs * p.y;
        p = bfpair(r.w); acc[6] += exs * p.x; acc[7] += exs * p.y;
        float inv = 1.f / (den + 1e-16f);
        short ov[8];
        #pragma unroll
        for (int k = 0; k < 8; k++) {
            float va = acc[k] * inv + b1[hl * 8 + k];
            va = (va > 0.f) ? va : __expf(va) - 1.f;   // ELU (natural e)
            ov[k] = (short)f2bf(va);
        }
        bf16x8 o8 = {ov[0], ov[1], ov[2], ov[3], ov[4], ov[5], ov[6], ov[7]};
        *(bf16x8*)(h2b + (size_t)node * 256 + hl * 8) = o8;
    }
}

// ---------------- layer2 fused softmax+aggregate+bias (H=1, 128ch, fp32 out) --
// quarter-wave per edge (full 256B row per 16 lanes); rotating clamped slot
// prefetch; exp2-domain alphas.
__global__ __launch_bounds__(256) void k_agg2(const int* __restrict__ rowptr,
                       const int2* __restrict__ slot, const float* __restrict__ asrc,
                       const float* __restrict__ adst, const float* __restrict__ v,
                       const unsigned short* __restrict__ gb, const float* __restrict__ b2,
                       float* __restrict__ outp) {
    int node = blockIdx.x * 4 + (threadIdx.x >> 6);
    if (node >= NN) return;
    int lane = threadIdx.x & 63;
    int q  = lane >> 4;          // edge-in-group
    int ql = lane & 15;          // channel-lane (8 ch each)
    int beg = rowptr[node], end = rowptr[node + 1];
    float ad = adst[node];
    float v0 = v[0], v1 = v[1];
    float acc[8] = {};
    float den = 0.f, s0 = 0.f, s1 = 0.f;
    const unsigned short* gbq = gb + ql * 8;

    int cnt = end - beg;
    int safeLast = max(end - 1, 0);
    int mend = beg + (cnt & ~3);

    int2 sl0 = slot[min(beg + q, safeLast)];
    int2 sl1 = slot[min(beg + 4 + q, safeLast)];

    auto body = [&](int2 cur) {
        int s = cur.x;
        float2 a = bfpair((unsigned)cur.y);
        float al = asrc[s] + ad + a.x * v0 + a.y * v1;
        al = (al > 0.f) ? al : 0.2f * al;
        float e = __builtin_amdgcn_exp2f(al);
        s0 += a.x; s1 += a.y; den += e;
        uint4 r = *(const uint4*)(gbq + (size_t)s * 128);
        float2 p;
        p = bfpair(r.x); acc[0] += e * p.x; acc[1] += e * p.y;
        p = bfpair(r.y); acc[2] += e * p.x; acc[3] += e * p.y;
        p = bfpair(r.z); acc[4] += e * p.x; acc[5] += e * p.y;
        p = bfpair(r.w); acc[6] += e * p.x; acc[7] += e * p.y;
    };

    #pragma unroll 2
    for (int pb = beg; pb < mend; pb += 4) {
        int2 cur = sl0;
        sl0 = sl1;
        sl1 = slot[min(pb + 8 + q, safeLast)];
        body(cur);
    }
    if (mend + q < end) body(sl0);          // tail edges

    #pragma unroll
    for (int k = 0; k < 8; k++) {
        acc[k] += __shfl_down(acc[k], 32);
        acc[k] += __shfl_down(acc[k], 16);
    }
    den += __shfl_xor(den, 16); den += __shfl_xor(den, 32);
    s0  += __shfl_xor(s0, 16);  s0  += __shfl_xor(s0, 32);
    s1  += __shfl_xor(s1, 16);  s1  += __shfl_xor(s1, 32);

    // self-loop epilogue
    float dg = fmaxf((float)cnt, 1.0f);
    float als = asrc[node] + ad + (s0 / dg) * v0 + (s1 / dg) * v1;
    als = (als > 0.f) ? als : 0.2f * als;
    float exs = __builtin_amdgcn_exp2f(als);
    den += exs;

    if (q == 0) {
        uint4 r = *(const uint4*)(gbq + (size_t)node * 128);
        float2 p;
        p = bfpair(r.x); acc[0] += exs * p.x; acc[1] += exs * p.y;
        p = bfpair(r.y); acc[2] += exs * p.x; acc[3] += exs * p.y;
        p = bfpair(r.z); acc[4] += exs * p.x; acc[5] += exs * p.y;
        p = bfpair(r.w); acc[6] += exs * p.x; acc[7] += exs * p.y;
        float inv = 1.f / (den + 1e-16f);
        float4 o0, o1;
        o0.x = acc[0] * inv + b2[ql * 8 + 0];
        o0.y = acc[1] * inv + b2[ql * 8 + 1];
        o0.z = acc[2] * inv + b2[ql * 8 + 2];
        o0.w = acc[3] * inv + b2[ql * 8 + 3];
        o1.x = acc[4] * inv + b2[ql * 8 + 4];
        o1.y = acc[5] * inv + b2[ql * 8 + 5];
        o1.z = acc[6] * inv + b2[ql * 8 + 6];
        o1.w = acc[7] * inv + b2[ql * 8 + 7];
        *(float4*)(outp + (size_t)node * 128 + ql * 8)     = o0;
        *(float4*)(outp + (size_t)node * 128 + ql * 8 + 4) = o1;
    }
}

extern "C" void kernel_launch(void* const* d_in, const int* in_sizes, int n_in,
                              void* d_out, int out_size, void* d_ws, size_t ws_size,
                              hipStream_t stream) {
    const float* x     = (const float*)d_in[0];
    const int*   ei    = (const int*)d_in[1];      // int32 on device
    const float* eattr = (const float*)d_in[2];
    const float* W1    = (const float*)d_in[3];
    const float* We1   = (const float*)d_in[4];
    const float* as1   = (const float*)d_in[5];
    const float* ad1   = (const float*)d_in[6];
    const float* ae1   = (const float*)d_in[7];
    const float* b1    = (const float*)d_in[8];
    const float* W2    = (const float*)d_in[9];
    const float* We2   = (const float*)d_in[10];
    const float* as2   = (const float*)d_in[11];
    const float* ad2   = (const float*)d_in[12];
    const float* ae2   = (const float*)d_in[13];
    const float* b2    = (const float*)d_in[14];
    float* out = (float*)d_out;

    // ---- workspace carve ----
    int* idg    = (int*)d_ws;                      // NN
    int* rank   = idg + NN;                        // EE
    int* rowptr = rank + EE;                       // NN+16
    int* bsum   = rowptr + NN + 16;                // 32
    int* boff   = bsum + 32;                       // 32
    int2* slot  = (int2*)(boff + 32);              // EE (8B-aligned)
    float* asrc1 = (float*)(slot + EE);            // 4*NN
    float* adst1 = asrc1 + 4 * NN;                 // 4*NN
    float* asrc2 = adst1 + 4 * NN;                 // NN
    float* adst2 = asrc2 + NN;                     // NN
    float* vbuf  = adst2 + NN;                     // 64
    unsigned short* ub = (unsigned short*)(((uintptr_t)(vbuf + 64) + 63) & ~(uintptr_t)63);
    unsigned short* W1t   = ub;                      // 256*128
    unsigned short* W2t   = W1t + 32768;             // 128*256
    unsigned short* h1_bf = W2t + 32768;             // NN*256
    unsigned short* h2_bf = h1_bf + (size_t)NN * 256;// NN*256
    unsigned short* g2_bf = h2_bf + (size_t)NN * 256;// NN*128

    hipMemsetAsync(idg, 0, (size_t)NN * sizeof(int), stream);

    // prep (v, Wt casts, degree hist + rank) + CSR build (atomic-free)
    k_prep<<<3382, 256, 0, stream>>>(We1, ae1, We2, ae2, vbuf, W1, W1t, W2, W2t,
                                     ei, idg, rank);
    k_scan1<<<NB, 512, 0, stream>>>(idg, rowptr, bsum);
    k_scan2<<<1, 64, 0, stream>>>(bsum, boff, rowptr);
    k_scan3<<<NB, 512, 0, stream>>>(rowptr, boff);
    k_scatter<<<(EE + 255) / 256, 256, 0, stream>>>(ei, eattr, rowptr, rank, slot);

    // ---- layer 1 ----  (gemm reads fp32 x directly; fused attn scalars)
    gemm_mfma<128, 4, 4, float><<<dim3(4, (NN + 127) / 128), 256, 0, stream>>>(
        x, W1t, h1_bf, as1, ad1, asrc1, adst1, NN, 256);
    k_agg1<<<(NN + 3) / 4, 256, 0, stream>>>(rowptr, slot, asrc1, adst1, vbuf,
                                             h1_bf, b1, h2_bf);

    // ---- layer 2 ----
    gemm_mfma<256, 8, 1, unsigned short><<<dim3(1, (NN + 127) / 128), 256, 0, stream>>>(
        h2_bf, W2t, g2_bf, as2, ad2, asrc2, adst2, NN, 128);
    k_agg2<<<(NN + 3) / 4, 256, 0, stream>>>(rowptr, slot, asrc2, adst2, vbuf + 8,
                                             g2_bf, b2, out);
}